// Round 3
// baseline (401.448 us; speedup 1.0000x reference)
//
#include <hip/hip_runtime.h>
#include <stdint.h>

#define THR  1.0f
#define BETA 0.95f

typedef __attribute__((ext_vector_type(8)))  short  bf16x8;
typedef __attribute__((ext_vector_type(16))) float  f32x16;
typedef __attribute__((ext_vector_type(4)))  float  fvec4;

// Exact 3-way truncated bf16 split: w == wh + wm + wl exactly (24 = 3x8 mantissa bits).
__global__ void split_w1(const float* __restrict__ W1,
                         unsigned short* __restrict__ wh,
                         unsigned short* __restrict__ wm,
                         unsigned short* __restrict__ wl){
  int i = blockIdx.x * 256 + threadIdx.x;
  if (i < 128 * 784) {
    float v = W1[i];
    uint32_t u  = __float_as_uint(v);
    uint32_t uh = u & 0xFFFF0000u;
    float vm = v - __uint_as_float(uh);
    uint32_t um = __float_as_uint(vm) & 0xFFFF0000u;
    float vl = vm - __uint_as_float(um);          // exactly representable in bf16
    wh[i] = (unsigned short)(uh >> 16);
    wm[i] = (unsigned short)(um >> 16);
    wl[i] = (unsigned short)(__float_as_uint(vl) >> 16);
  }
}

// cur1[m][h] = sum_k x[row0+m][k] * W1[h][k]   (bias added later in lif)
// Wave tile 32(M) x 128(N), block = 4 waves stacked in M -> 128-row block tile.
// acc = 64 AGPR/wave -> 3 waves/SIMD occupancy. No LDS.
// 6-term exact-split MFMA: hh + hm + mh + mm + hl + lh (drops only <=2^-24 rel terms).
__launch_bounds__(256, 3)
__global__ void gemm1(const float* __restrict__ x,
                      const unsigned short* __restrict__ wh,
                      const unsigned short* __restrict__ wm,
                      const unsigned short* __restrict__ wl,
                      float* __restrict__ cur1,
                      long row0){
  const int lane = threadIdx.x & 63;
  const int wid  = threadIdx.x >> 6;
  const long m0  = (long)blockIdx.x * 128 + (long)wid * 32;
  const int r  = lane & 31;   // row (A) / col (B) within 32-frag
  const int kg = lane >> 5;   // k-group: 8 contiguous k per lane

  const float* xr0 = x + (row0 + m0 + r) * 784 + kg * 8;
  const int wbase[4] = { (0 * 32 + r) * 784 + kg * 8,
                         (1 * 32 + r) * 784 + kg * 8,
                         (2 * 32 + r) * 784 + kg * 8,
                         (3 * 32 + r) * 784 + kg * 8 };

  f32x16 acc[4] = {};

  for (int k0 = 0; k0 < 784; k0 += 16) {
    bf16x8 bh[4], bm[4], bl[4];
    #pragma unroll
    for (int nf = 0; nf < 4; ++nf) {
      bh[nf] = *(const bf16x8*)(wh + wbase[nf] + k0);
      bm[nf] = *(const bf16x8*)(wm + wbase[nf] + k0);
      bl[nf] = *(const bf16x8*)(wl + wbase[nf] + k0);
    }
    const float* p = xr0 + k0;
    fvec4 a0 = *(const fvec4*)(p);
    fvec4 a1 = *(const fvec4*)(p + 4);
    bf16x8 ah, am, al;
    #pragma unroll
    for (int j = 0; j < 8; ++j) {
      float v = (j < 4) ? a0[j] : a1[j - 4];
      uint32_t u  = __float_as_uint(v);
      uint32_t uh = u & 0xFFFF0000u;
      float vm = v - __uint_as_float(uh);
      uint32_t um = __float_as_uint(vm) & 0xFFFF0000u;
      float vl = vm - __uint_as_float(um);
      ah[j] = (short)(uh >> 16);
      am[j] = (short)(um >> 16);
      al[j] = (short)(__float_as_uint(vl) >> 16);
    }
    #pragma unroll
    for (int nf = 0; nf < 4; ++nf) {
      acc[nf] = __builtin_amdgcn_mfma_f32_32x32x16_bf16(ah, bh[nf], acc[nf], 0, 0, 0);
      acc[nf] = __builtin_amdgcn_mfma_f32_32x32x16_bf16(ah, bm[nf], acc[nf], 0, 0, 0);
      acc[nf] = __builtin_amdgcn_mfma_f32_32x32x16_bf16(am, bh[nf], acc[nf], 0, 0, 0);
      acc[nf] = __builtin_amdgcn_mfma_f32_32x32x16_bf16(am, bm[nf], acc[nf], 0, 0, 0);
      acc[nf] = __builtin_amdgcn_mfma_f32_32x32x16_bf16(ah, bl[nf], acc[nf], 0, 0, 0);
      acc[nf] = __builtin_amdgcn_mfma_f32_32x32x16_bf16(al, bh[nf], acc[nf], 0, 0, 0);
    }
  }

  // C/D layout (m74/m101-verified): col = lane&31, row = (reg&3) + 8*(reg>>2) + 4*(lane>>5)
  #pragma unroll
  for (int nf = 0; nf < 4; ++nf)
    #pragma unroll
    for (int reg = 0; reg < 16; ++reg) {
      int row = (reg & 3) + 8 * (reg >> 2) + 4 * kg;
      long m = m0 + row;
      cur1[m * 128 + nf * 32 + r] = acc[nf][reg];
    }
}

// LIF recurrence + layer 2. One wave per batch element b; lane owns h=lane, h=lane+64.
// Layer-2 reduction via ballot bitmask + per-lane 32-bit chunk weight sums.
__launch_bounds__(256)
__global__ void lif(const float* __restrict__ cur1,
                    const float* __restrict__ b1,
                    const float* __restrict__ W2,
                    const float* __restrict__ b2,
                    float* __restrict__ out,
                    float* __restrict__ state1,
                    float* __restrict__ state2,
                    int t0, int tn){
  const int lane = threadIdx.x & 63;
  const int b = blockIdx.x * 4 + (threadIdx.x >> 6);
  const int o = lane & 15;    // output index this lane accumulates (valid if <10)
  const int c = lane >> 4;    // h-chunk 0..3 (32 h each)

  float wv[32];
  #pragma unroll
  for (int j = 0; j < 32; ++j) wv[j] = 0.f;
  if (o < 10) {
    #pragma unroll
    for (int j = 0; j < 32; ++j) wv[j] = W2[o * 128 + c * 32 + j];
  }
  float b1a = b1[lane], b1b = b1[64 + lane];
  float b2v = (lane < 10) ? b2[lane] : 0.f;

  float mem1a, mem1b, mem2;
  if (t0 == 0) { mem1a = 0.f; mem1b = 0.f; mem2 = 0.f; }
  else {
    mem1a = state1[b * 128 + lane];
    mem1b = state1[b * 128 + 64 + lane];
    mem2  = (lane < 10) ? state2[b * 10 + lane] : 0.f;
  }

  for (int t = t0; t < tn; ++t) {
    long base = ((long)(t - t0) * 4096 + b) * 128;
    float c1a = cur1[base + lane] + b1a;
    float c1b = cur1[base + 64 + lane] + b1b;
    float r1a = (mem1a > THR) ? THR : 0.f;   // reset uses OLD mem
    float r1b = (mem1b > THR) ? THR : 0.f;
    mem1a = BETA * mem1a + c1a - r1a;
    mem1b = BETA * mem1b + c1b - r1b;

    uint64_t mA = __ballot(mem1a > THR);  // spk1 bits for h = lane
    uint64_t mB = __ballot(mem1b > THR);  // spk1 bits for h = 64 + lane
    uint64_t m64 = (c & 2) ? mB : mA;
    uint32_t bits = (uint32_t)(m64 >> ((c & 1) << 5));

    float s = 0.f;
    #pragma unroll
    for (int j = 0; j < 32; ++j) {
      int msk = (int)(bits << (31 - j)) >> 31;           // -(bit j)
      s += __int_as_float(msk & __float_as_int(wv[j]));  // + wv[j] or +0
    }
    // combine the 4 chunks (lanes l, l^16, l^32, l^48 share o)
    s += __shfl_xor(s, 16);
    s += __shfl_xor(s, 32);

    if (lane < 10) {
      float cur2 = s + b2v;
      float r2 = (mem2 > THR) ? THR : 0.f;
      mem2 = BETA * mem2 + cur2 - r2;
      float s2 = (mem2 > THR) ? 1.f : 0.f;
      long ob = (long)t * 40960 + (long)b * 10 + lane;
      out[ob] = s2;
      out[1228800 + ob] = mem2;
    }
  }

  if (tn < 30) {
    state1[b * 128 + lane] = mem1a;
    state1[b * 128 + 64 + lane] = mem1b;
    if (lane < 10) state2[b * 10 + lane] = mem2;
  }
}

extern "C" void kernel_launch(void* const* d_in, const int* in_sizes, int n_in,
                              void* d_out, int out_size, void* d_ws, size_t ws_size,
                              hipStream_t stream) {
  const float* x  = (const float*)d_in[0];
  const float* W1 = (const float*)d_in[1];
  const float* b1 = (const float*)d_in[2];
  const float* W2 = (const float*)d_in[3];
  const float* b2 = (const float*)d_in[4];
  float* out = (float*)d_out;

  const int T = 30, B = 4096;
  const int W1N = 128 * 784;

  char* ws = (char*)d_ws;
  unsigned short* wh = (unsigned short*)ws;
  unsigned short* wm = wh + W1N;
  unsigned short* wl = wm + W1N;
  size_t off = (size_t)3 * W1N * sizeof(unsigned short);
  off = (off + 255) & ~(size_t)255;
  float* state1 = (float*)(ws + off); off += (size_t)B * 128 * 4;
  float* state2 = (float*)(ws + off); off += (size_t)B * 10 * 4;
  off = (off + 255) & ~(size_t)255;
  float* cur1 = (float*)(ws + off);

  size_t per_t = (size_t)B * 128 * 4;
  size_t avail = (ws_size > off) ? (ws_size - off) : 0;
  int CH = (int)(avail / per_t);
  if (CH > T) CH = T;
  if (CH < 1) CH = 1;

  split_w1<<<(W1N + 255) / 256, 256, 0, stream>>>(W1, wh, wm, wl);

  for (int t0 = 0; t0 < T; t0 += CH) {
    int tn = (t0 + CH < T) ? (t0 + CH) : T;
    int mrows = (tn - t0) * B;                   // multiple of 4096 -> multiple of 128
    gemm1<<<mrows / 128, 256, 0, stream>>>(x, wh, wm, wl, cur1, (long)t0 * B);
    lif<<<B / 4, 256, 0, stream>>>(cur1, b1, W2, b2, out, state1, state2, t0, tn);
  }
}

// Round 4
// 330.801 us; speedup vs baseline: 1.2136x; 1.2136x over previous
//
#include <hip/hip_runtime.h>
#include <stdint.h>

#define THR  1.0f
#define BETA 0.95f
#define SX   4096.0f            // x scale (2^12) -> no fp16 denormal flush risk
#define SW   512.0f             // W scale (2^9)
#define SINV (1.0f / (4096.0f * 512.0f))
#define W1N  (128 * 784)

typedef __attribute__((ext_vector_type(8)))  _Float16 f16x8;
typedef __attribute__((ext_vector_type(16))) float    f32x16;
typedef __attribute__((ext_vector_type(4)))  float    fvec4;

// 2-term RNE fp16 split of scaled W: W*SW == wh + wl exact to ~2^-25 rel.
__global__ void split_w1(const float* __restrict__ W1, _Float16* __restrict__ w){
  int i = blockIdx.x * 256 + threadIdx.x;
  if (i < W1N) {
    float v = W1[i] * SW;
    _Float16 h = (_Float16)v;        // RNE
    float r = v - (float)h;          // exact
    w[i] = h;
    w[W1N + i] = (_Float16)r;        // RNE, exact to 2^-25 rel
  }
}

// cur1[m][h] = sum_k x[m][k] * W1[h][k]  (scaled; bias added in lif)
// Wave tile 32m x 128n. Software-pipelined: A prefetch distance 3 (HBM),
// B prefetch distance 1 (L2). 3 fp16 MFMAs (hh+hl+lh) per nf per k-step.
#define LDA(Pa, Pb, kk) { int kc = (kk); if (kc > 768) kc = 768;            \
    const float* p = xr + kc; Pa = *(const fvec4*)p; Pb = *(const fvec4*)(p + 4); }

#define LDB(Bf, kk) { int kc = (kk);                                        \
    _Pragma("unroll") for (int nf = 0; nf < 4; ++nf) {                      \
      Bf[nf]     = *(const f16x8*)(w   + wb[nf] + kc);                      \
      Bf[nf + 4] = *(const f16x8*)(wlo + wb[nf] + kc); } }

#define SPLIT(Pa, Pb, H, L) {                                               \
    _Pragma("unroll") for (int j = 0; j < 8; ++j) {                         \
      float v = ((j < 4) ? Pa[j] : Pb[j - 4]) * SX;                         \
      _Float16 hh = (_Float16)v;                                            \
      float rr = v - (float)hh;                                             \
      H[j] = hh; L[j] = (_Float16)rr; } }

#define STEP(Ua, Ub, Bu, Bn, La, Lb, kk) {                                  \
    LDB(Bn, (kk) + 16);                                                     \
    LDA(La, Lb, (kk) + 48);                                                 \
    f16x8 ah, al; SPLIT(Ua, Ub, ah, al);                                    \
    _Pragma("unroll") for (int nf = 0; nf < 4; ++nf) {                      \
      acc[nf] = __builtin_amdgcn_mfma_f32_32x32x16_f16(ah, Bu[nf],     acc[nf], 0, 0, 0); \
      acc[nf] = __builtin_amdgcn_mfma_f32_32x32x16_f16(ah, Bu[nf + 4], acc[nf], 0, 0, 0); \
      acc[nf] = __builtin_amdgcn_mfma_f32_32x32x16_f16(al, Bu[nf],     acc[nf], 0, 0, 0); } }

__launch_bounds__(256, 2)
__global__ void gemm1(const float* __restrict__ x,
                      const _Float16* __restrict__ w,   // [2][128][784] hi, lo
                      float* __restrict__ cur1,
                      long row0){
  const int lane = threadIdx.x & 63;
  const int wid  = threadIdx.x >> 6;
  const long m0  = (long)blockIdx.x * 128 + (long)wid * 32;
  const int r  = lane & 31;   // A row / B col within 32-frag
  const int kg = lane >> 5;   // k-group: 8 contiguous k per lane

  const float* xr = x + (row0 + m0 + r) * 784 + kg * 8;
  const int wb[4] = { (0 * 32 + r) * 784 + kg * 8,
                      (1 * 32 + r) * 784 + kg * 8,
                      (2 * 32 + r) * 784 + kg * 8,
                      (3 * 32 + r) * 784 + kg * 8 };
  const _Float16* wlo = w + W1N;

  f32x16 acc[4] = {};
  fvec4 A0a, A0b, A1a, A1b, A2a, A2b, A3a, A3b;
  f16x8 B0[8], B1[8];

  LDA(A0a, A0b, 0); LDA(A1a, A1b, 16); LDA(A2a, A2b, 32);
  LDB(B0, 0);

  int k = 0;
  for (int it = 0; it < 12; ++it) {
    STEP(A0a, A0b, B0, B1, A3a, A3b, k);
    STEP(A1a, A1b, B1, B0, A0a, A0b, k + 16);
    STEP(A2a, A2b, B0, B1, A1a, A1b, k + 32);
    STEP(A3a, A3b, B1, B0, A2a, A2b, k + 48);
    k += 64;
  }
  // tail k-step 48 (k=768): uses A0 / B0, no further loads
  {
    f16x8 ah, al; SPLIT(A0a, A0b, ah, al);
    #pragma unroll
    for (int nf = 0; nf < 4; ++nf) {
      acc[nf] = __builtin_amdgcn_mfma_f32_32x32x16_f16(ah, B0[nf],     acc[nf], 0, 0, 0);
      acc[nf] = __builtin_amdgcn_mfma_f32_32x32x16_f16(ah, B0[nf + 4], acc[nf], 0, 0, 0);
      acc[nf] = __builtin_amdgcn_mfma_f32_32x32x16_f16(al, B0[nf],     acc[nf], 0, 0, 0);
    }
  }

  // C/D layout (m74/m101-verified): col = lane&31, row = (reg&3) + 8*(reg>>2) + 4*(lane>>5)
  #pragma unroll
  for (int nf = 0; nf < 4; ++nf)
    #pragma unroll
    for (int reg = 0; reg < 16; ++reg) {
      int row = (reg & 3) + 8 * (reg >> 2) + 4 * kg;
      cur1[(m0 + row) * 128 + nf * 32 + r] = acc[nf][reg] * SINV;
    }
}

// LIF recurrence + layer 2. One wave per batch element b; lane owns h=lane, h=lane+64.
// Layer-2 reduction via ballot bitmask + per-lane 32-bit chunk weight sums.
__launch_bounds__(256)
__global__ void lif(const float* __restrict__ cur1,
                    const float* __restrict__ b1,
                    const float* __restrict__ W2,
                    const float* __restrict__ b2,
                    float* __restrict__ out,
                    float* __restrict__ state1,
                    float* __restrict__ state2,
                    int t0, int tn){
  const int lane = threadIdx.x & 63;
  const int b = blockIdx.x * 4 + (threadIdx.x >> 6);
  const int o = lane & 15;
  const int c = lane >> 4;

  float wv[32];
  #pragma unroll
  for (int j = 0; j < 32; ++j) wv[j] = 0.f;
  if (o < 10) {
    #pragma unroll
    for (int j = 0; j < 32; ++j) wv[j] = W2[o * 128 + c * 32 + j];
  }
  float b1a = b1[lane], b1b = b1[64 + lane];
  float b2v = (lane < 10) ? b2[lane] : 0.f;

  float mem1a, mem1b, mem2;
  if (t0 == 0) { mem1a = 0.f; mem1b = 0.f; mem2 = 0.f; }
  else {
    mem1a = state1[b * 128 + lane];
    mem1b = state1[b * 128 + 64 + lane];
    mem2  = (lane < 10) ? state2[b * 10 + lane] : 0.f;
  }

  for (int t = t0; t < tn; ++t) {
    long base = ((long)(t - t0) * 4096 + b) * 128;
    float c1a = cur1[base + lane] + b1a;
    float c1b = cur1[base + 64 + lane] + b1b;
    float r1a = (mem1a > THR) ? THR : 0.f;
    float r1b = (mem1b > THR) ? THR : 0.f;
    mem1a = BETA * mem1a + c1a - r1a;
    mem1b = BETA * mem1b + c1b - r1b;

    uint64_t mA = __ballot(mem1a > THR);
    uint64_t mB = __ballot(mem1b > THR);
    uint64_t m64 = (c & 2) ? mB : mA;
    uint32_t bits = (uint32_t)(m64 >> ((c & 1) << 5));

    float s = 0.f;
    #pragma unroll
    for (int j = 0; j < 32; ++j) {
      int msk = (int)(bits << (31 - j)) >> 31;
      s += __int_as_float(msk & __float_as_int(wv[j]));
    }
    s += __shfl_xor(s, 16);
    s += __shfl_xor(s, 32);

    if (lane < 10) {
      float cur2 = s + b2v;
      float r2 = (mem2 > THR) ? THR : 0.f;
      mem2 = BETA * mem2 + cur2 - r2;
      float s2 = (mem2 > THR) ? 1.f : 0.f;
      long ob = (long)t * 40960 + (long)b * 10 + lane;
      out[ob] = s2;
      out[1228800 + ob] = mem2;
    }
  }

  if (tn < 30) {
    state1[b * 128 + lane] = mem1a;
    state1[b * 128 + 64 + lane] = mem1b;
    if (lane < 10) state2[b * 10 + lane] = mem2;
  }
}

extern "C" void kernel_launch(void* const* d_in, const int* in_sizes, int n_in,
                              void* d_out, int out_size, void* d_ws, size_t ws_size,
                              hipStream_t stream) {
  const float* x  = (const float*)d_in[0];
  const float* W1 = (const float*)d_in[1];
  const float* b1 = (const float*)d_in[2];
  const float* W2 = (const float*)d_in[3];
  const float* b2 = (const float*)d_in[4];
  float* out = (float*)d_out;

  const int T = 30, B = 4096;

  char* ws = (char*)d_ws;
  _Float16* w16 = (_Float16*)ws;                 // [2][W1N]
  size_t off = (size_t)2 * W1N * sizeof(_Float16);
  off = (off + 255) & ~(size_t)255;
  float* state1 = (float*)(ws + off); off += (size_t)B * 128 * 4;
  float* state2 = (float*)(ws + off); off += (size_t)B * 10 * 4;
  off = (off + 255) & ~(size_t)255;
  float* cur1 = (float*)(ws + off);

  size_t per_t = (size_t)B * 128 * 4;
  size_t avail = (ws_size > off) ? (ws_size - off) : 0;
  int CH = (int)(avail / per_t);
  if (CH > T) CH = T;
  if (CH < 1) CH = 1;

  split_w1<<<(W1N + 255) / 256, 256, 0, stream>>>(W1, w16);

  for (int t0 = 0; t0 < T; t0 += CH) {
    int tn = (t0 + CH < T) ? (t0 + CH) : T;
    int mrows = (tn - t0) * B;                   // multiple of 4096 -> multiple of 128
    gemm1<<<mrows / 128, 256, 0, stream>>>(x, w16, cur1, (long)t0 * B);
    lif<<<B / 4, 256, 0, stream>>>(cur1, b1, W2, b2, out, state1, state2, t0, tn);
  }
}

// Round 5
// 181.918 us; speedup vs baseline: 2.2068x; 1.8184x over previous
//
#include <hip/hip_runtime.h>
#include <stdint.h>

#define THR  1.0f
#define BETA 0.95f
#define SX   4096.0f            // x scale (2^12) -> no fp16 denormal flush
#define SW   512.0f             // W scale (2^9)
#define SINV (1.0f / (4096.0f * 512.0f))
#define W1N  (128 * 784)

typedef __attribute__((ext_vector_type(8)))  _Float16 f16x8;
typedef __attribute__((ext_vector_type(16))) float    f32x16;
typedef __attribute__((ext_vector_type(4)))  float    fvec4;

__device__ __forceinline__ void gll16(const float* g, float* l){
  __builtin_amdgcn_global_load_lds((const __attribute__((address_space(1))) void*)g,
                                   (__attribute__((address_space(3))) void*)l, 16, 0, 0);
}

// 2-term RNE fp16 split of scaled W1, written in MFMA-fragment order:
// wB fragment (ks 0..48, nf 0..3, term 0..1) is 1KB: lane (kg*32+r) holds 8 fp16
// for col h=nf*32+r, k=ks*16+kg*8.. — so a wave's B-load is 1KB fully contiguous.
__global__ void split_w1(const float* __restrict__ W1, _Float16* __restrict__ wB){
  int i = blockIdx.x * 256 + threadIdx.x;
  if (i < W1N) {
    int h = i / 784, k = i % 784;
    float v = W1[i] * SW;
    _Float16 hi = (_Float16)v;
    _Float16 lo = (_Float16)(v - (float)hi);
    int ks = k >> 4, kg = (k >> 3) & 1, j = k & 7, nf = h >> 5, r = h & 31;
    int base = ((ks * 4 + nf) * 2) * 512 + (kg * 32 + r) * 8 + j;
    wB[base]       = hi;   // term 0
    wB[base + 512] = lo;   // term 1
  }
}

// cur1[m][h] = sum_k x[m][k]*W1[h][k] (scaled; bias in lif).
// Block: 4 waves, tile 128m x 128n. A staged via global_load_lds into swizzled
// 128x64 f32 LDS slabs (double-buffered, 2-phase). Tail k=768..783 staged once.
// 3 fp16 MFMAs (hh+hl+lh) per nf per k-step.
__launch_bounds__(256, 2)
__global__ void gemm1(const float* __restrict__ x,
                      const _Float16* __restrict__ wB,
                      float* __restrict__ cur1,
                      long row0){
  __shared__ float lds[18432];            // 2x8192 slab dbuf + 2048 tail = 72KB
  const int lane = threadIdx.x & 63;
  const int w    = threadIdx.x >> 6;
  const long blk_row0 = row0 + (long)blockIdx.x * 128;
  const int r  = lane & 31;
  const int kg = lane >> 5;
  const int row_a = w * 32 + r;           // this lane's A row within tile
  const int xr  = (row_a & 7) << 4;       // main-slab XOR swizzle (bytes)
  const int xr3 = (row_a & 3) << 4;       // tail XOR swizzle
  const f16x8* wv = (const f16x8*)wB;

  // ---- stage tail (k=768..783) into lds[16384..] : 2 instrs/wave ----
  #pragma unroll
  for (int i = 0; i < 2; ++i) {
    int j = (w * 2 + i) * 64 + lane;      // 0..511
    int rw = j >> 2, q = (j & 3) << 4;
    int kb = q ^ ((rw & 3) << 4);
    gll16(x + (blk_row0 + rw) * 784 + 768 + (kb >> 2),
          &lds[16384 + (w * 2 + i) * 256]);
  }

  #define STAGE(bb, s) {                                                     \
    _Pragma("unroll") for (int i = 0; i < 8; ++i) {                          \
      int j = (w * 8 + i) * 64 + lane;                                       \
      int rw = j >> 4, q = (j & 15) << 4;                                    \
      int kb = q ^ ((rw & 7) << 4);                                          \
      gll16(x + (blk_row0 + rw) * 784 + (s) * 64 + (kb >> 2),                \
            &lds[(bb) * 8192 + (w * 8 + i) * 256]); } }

  f32x16 acc[4] = {};

  STAGE(0, 0);
  __syncthreads();                        // full drain: slab 0 (and tail issued) ready

  #pragma unroll 2
  for (int s = 0; s < 12; ++s) {
    const int bb = s & 1;
    if (s + 1 < 12) STAGE(bb ^ 1, s + 1); // async prefetch next slab
    #pragma unroll
    for (int ks = 0; ks < 4; ++ks) {
      // B fragments: 8 x 1KB contiguous wave-loads (L2-hot)
      f16x8 b[8];
      #pragma unroll
      for (int nf = 0; nf < 4; ++nf) {
        #pragma unroll
        for (int t = 0; t < 2; ++t)
          b[nf * 2 + t] = wv[(((s * 4 + ks) * 4 + nf) * 2 + t) * 64 + lane];
      }
      // A fragment: 2 swizzled ds_read_b128 + fp16 split
      int kb0 = ks * 64 + kg * 32;
      fvec4 a0 = *(const fvec4*)&lds[bb * 8192 + row_a * 64 + (((kb0)      ^ xr) >> 2)];
      fvec4 a1 = *(const fvec4*)&lds[bb * 8192 + row_a * 64 + (((kb0 + 16) ^ xr) >> 2)];
      f16x8 ah, al;
      #pragma unroll
      for (int j = 0; j < 8; ++j) {
        float v = ((j < 4) ? a0[j] : a1[j - 4]) * SX;
        _Float16 hh = (_Float16)v;
        ah[j] = hh; al[j] = (_Float16)(v - (float)hh);
      }
      #pragma unroll
      for (int nf = 0; nf < 4; ++nf) {
        acc[nf] = __builtin_amdgcn_mfma_f32_32x32x16_f16(ah, b[nf * 2],     acc[nf], 0, 0, 0);
        acc[nf] = __builtin_amdgcn_mfma_f32_32x32x16_f16(ah, b[nf * 2 + 1], acc[nf], 0, 0, 0);
        acc[nf] = __builtin_amdgcn_mfma_f32_32x32x16_f16(al, b[nf * 2],     acc[nf], 0, 0, 0);
      }
    }
    __syncthreads();                      // drains vmcnt(0): next slab staged, buf free
  }

  // ---- tail k-step (global ks=48) from tail LDS region ----
  {
    f16x8 b[8];
    #pragma unroll
    for (int nf = 0; nf < 4; ++nf)
      #pragma unroll
      for (int t = 0; t < 2; ++t)
        b[nf * 2 + t] = wv[((48 * 4 + nf) * 2 + t) * 64 + lane];
    int kb0 = kg * 32;
    fvec4 a0 = *(const fvec4*)&lds[16384 + row_a * 16 + (((kb0)      ^ xr3) >> 2)];
    fvec4 a1 = *(const fvec4*)&lds[16384 + row_a * 16 + (((kb0 + 16) ^ xr3) >> 2)];
    f16x8 ah, al;
    #pragma unroll
    for (int j = 0; j < 8; ++j) {
      float v = ((j < 4) ? a0[j] : a1[j - 4]) * SX;
      _Float16 hh = (_Float16)v;
      ah[j] = hh; al[j] = (_Float16)(v - (float)hh);
    }
    #pragma unroll
    for (int nf = 0; nf < 4; ++nf) {
      acc[nf] = __builtin_amdgcn_mfma_f32_32x32x16_f16(ah, b[nf * 2],     acc[nf], 0, 0, 0);
      acc[nf] = __builtin_amdgcn_mfma_f32_32x32x16_f16(ah, b[nf * 2 + 1], acc[nf], 0, 0, 0);
      acc[nf] = __builtin_amdgcn_mfma_f32_32x32x16_f16(al, b[nf * 2],     acc[nf], 0, 0, 0);
    }
  }

  // C/D layout (m74/m101-verified): col = lane&31, row = (reg&3)+8*(reg>>2)+4*(lane>>5)
  long m0 = (long)blockIdx.x * 128 + w * 32;
  #pragma unroll
  for (int nf = 0; nf < 4; ++nf)
    #pragma unroll
    for (int reg = 0; reg < 16; ++reg) {
      int rr = (reg & 3) + 8 * (reg >> 2) + 4 * kg;
      cur1[(m0 + rr) * 128 + nf * 32 + r] = acc[nf][reg] * SINV;
    }
  #undef STAGE
}

// LIF recurrence + layer 2 (unchanged).
__launch_bounds__(256)
__global__ void lif(const float* __restrict__ cur1,
                    const float* __restrict__ b1,
                    const float* __restrict__ W2,
                    const float* __restrict__ b2,
                    float* __restrict__ out,
                    float* __restrict__ state1,
                    float* __restrict__ state2,
                    int t0, int tn){
  const int lane = threadIdx.x & 63;
  const int b = blockIdx.x * 4 + (threadIdx.x >> 6);
  const int o = lane & 15;
  const int c = lane >> 4;

  float wv[32];
  #pragma unroll
  for (int j = 0; j < 32; ++j) wv[j] = 0.f;
  if (o < 10) {
    #pragma unroll
    for (int j = 0; j < 32; ++j) wv[j] = W2[o * 128 + c * 32 + j];
  }
  float b1a = b1[lane], b1b = b1[64 + lane];
  float b2v = (lane < 10) ? b2[lane] : 0.f;

  float mem1a, mem1b, mem2;
  if (t0 == 0) { mem1a = 0.f; mem1b = 0.f; mem2 = 0.f; }
  else {
    mem1a = state1[b * 128 + lane];
    mem1b = state1[b * 128 + 64 + lane];
    mem2  = (lane < 10) ? state2[b * 10 + lane] : 0.f;
  }

  for (int t = t0; t < tn; ++t) {
    long base = ((long)(t - t0) * 4096 + b) * 128;
    float c1a = cur1[base + lane] + b1a;
    float c1b = cur1[base + 64 + lane] + b1b;
    float r1a = (mem1a > THR) ? THR : 0.f;
    float r1b = (mem1b > THR) ? THR : 0.f;
    mem1a = BETA * mem1a + c1a - r1a;
    mem1b = BETA * mem1b + c1b - r1b;

    uint64_t mA = __ballot(mem1a > THR);
    uint64_t mB = __ballot(mem1b > THR);
    uint64_t m64 = (c & 2) ? mB : mA;
    uint32_t bits = (uint32_t)(m64 >> ((c & 1) << 5));

    float s = 0.f;
    #pragma unroll
    for (int j = 0; j < 32; ++j) {
      int msk = (int)(bits << (31 - j)) >> 31;
      s += __int_as_float(msk & __float_as_int(wv[j]));
    }
    s += __shfl_xor(s, 16);
    s += __shfl_xor(s, 32);

    if (lane < 10) {
      float cur2 = s + b2v;
      float r2 = (mem2 > THR) ? THR : 0.f;
      mem2 = BETA * mem2 + cur2 - r2;
      float s2 = (mem2 > THR) ? 1.f : 0.f;
      long ob = (long)t * 40960 + (long)b * 10 + lane;
      out[ob] = s2;
      out[1228800 + ob] = mem2;
    }
  }

  if (tn < 30) {
    state1[b * 128 + lane] = mem1a;
    state1[b * 128 + 64 + lane] = mem1b;
    if (lane < 10) state2[b * 10 + lane] = mem2;
  }
}

extern "C" void kernel_launch(void* const* d_in, const int* in_sizes, int n_in,
                              void* d_out, int out_size, void* d_ws, size_t ws_size,
                              hipStream_t stream) {
  const float* x  = (const float*)d_in[0];
  const float* W1 = (const float*)d_in[1];
  const float* b1 = (const float*)d_in[2];
  const float* W2 = (const float*)d_in[3];
  const float* b2 = (const float*)d_in[4];
  float* out = (float*)d_out;

  const int T = 30, B = 4096;

  char* ws = (char*)d_ws;
  _Float16* wB = (_Float16*)ws;                  // 49*8*512 fp16 = 392KB
  size_t off = (size_t)49 * 8 * 512 * sizeof(_Float16);
  off = (off + 255) & ~(size_t)255;
  float* state1 = (float*)(ws + off); off += (size_t)B * 128 * 4;
  float* state2 = (float*)(ws + off); off += (size_t)B * 10 * 4;
  off = (off + 255) & ~(size_t)255;
  float* cur1 = (float*)(ws + off);

  size_t per_t = (size_t)B * 128 * 4;
  size_t avail = (ws_size > off) ? (ws_size - off) : 0;
  int CH = (int)(avail / per_t);
  if (CH > T) CH = T;
  if (CH < 1) CH = 1;

  split_w1<<<(W1N + 255) / 256, 256, 0, stream>>>(W1, wB);

  for (int t0 = 0; t0 < T; t0 += CH) {
    int tn = (t0 + CH < T) ? (t0 + CH) : T;
    int mrows = (tn - t0) * B;                   // multiple of 4096 -> multiple of 128
    gemm1<<<mrows / 128, 256, 0, stream>>>(x, wB, cur1, (long)t0 * B);
    lif<<<B / 4, 256, 0, stream>>>(cur1, b1, W2, b2, out, state1, state2, t0, tn);
  }
}